// Round 10
// baseline (290.154 us; speedup 1.0000x reference)
//
#include <hip/hip_runtime.h>

#define EPS 1e-5f

typedef unsigned short ushort;
typedef unsigned int uint;
typedef __attribute__((ext_vector_type(8)))  short  short8;
typedef __attribute__((ext_vector_type(8)))  ushort ushort8;
typedef __attribute__((ext_vector_type(16))) float  f32x16;

// bf16 round-to-nearest-even split helpers
__device__ __forceinline__ ushort f2bf(float v) {
    uint b = __float_as_uint(v);
    return (ushort)((b + 0x7fffu + ((b >> 16) & 1u)) >> 16);
}
__device__ __forceinline__ float bf2f(ushort u) {
    return __uint_as_float(((uint)u) << 16);
}

// ---- prep: both W tensors -> per-lane MFMA B-fragment layout, bf16 hi/lo ----
// Wf[k][wc2][h][lane][j] : element = W[k][c][d],
//   d = wc2*32 + (lane&31),  c = h*16 + (lane>>5)*8 + j
// flat = (((k*2+wc2)*4+h)*64+lane)*8+j ; per (k,wc2,h) chunk = 1KB contiguous.
__global__ void prep_w2(const float* __restrict__ W1, const float* __restrict__ W2,
                        ushort* __restrict__ h1, ushort* __restrict__ l1,
                        ushort* __restrict__ h2, ushort* __restrict__ l2) {
    int e = blockIdx.x * 256 + threadIdx.x;   // 0 .. 2*36864-1
    const float* W = W1; ushort* ho = h1; ushort* lo = l1;
    if (e >= 36864) { e -= 36864; W = W2; ho = h2; lo = l2; }
    const int j = e & 7, l = (e >> 3) & 63, h = (e >> 9) & 3,
              wc2 = (e >> 11) & 1, k = e >> 12;
    const int d = wc2 * 32 + (l & 31);
    const int c = h * 16 + ((l >> 5) << 3) + j;
    const float v = W[(k << 12) + (c << 6) + d];
    const ushort hh = f2bf(v);
    ho[e] = hh;
    lo[e] = f2bf(v - bf2f(hh));
}

// out[n,d] = epilogue( sum_k sum_c f[nbr[n,k],c] * W[k,c,d] )
// 64 rows x 64 cols per block, 4 waves (2x2 of 32x32 MFMA tiles).
// Only the gathered A tile goes through LDS (18.4 KB -> 8 blocks/CU);
// B fragments come straight from L2 in prepped fragment layout.
template<bool SECOND>
__global__ __launch_bounds__(256, 8) void subm_conv_mfma(
    const float*  __restrict__ f,      // [N,64] fp32 (gathered)
    const int*    __restrict__ nbr,    // [N,9]
    const ushort* __restrict__ Wfh,    // fragment-layout bf16 hi
    const ushort* __restrict__ Wfl,    // fragment-layout bf16 lo
    const float*  __restrict__ gamma,
    const float*  __restrict__ beta,
    const float*  __restrict__ rmean,
    const float*  __restrict__ rvar,
    const float*  __restrict__ resid,  // x, only when SECOND
    float* __restrict__ out)           // [N,64] fp32
{
    __shared__ __align__(16) ushort Ah[64][72];
    __shared__ __align__(16) ushort Al[64][72];

    const int t    = threadIdx.x;
    const int lane = t & 63;
    const int w    = t >> 6;            // wave 0..3
    const int wr   = (w >> 1) << 5;     // wave row offset (0/32)
    const int wc2  = w & 1;             // wave col half (0/1)
    const int row0 = blockIdx.x << 6;

    const int sr = t >> 2;              // staging row (0..63)
    const int sc = (t & 3) << 4;        // staging c offset (0,16,32,48)

    f32x16 acc = 0.f;

    const int rA   = wr + (lane & 31);
    const int koff = (lane >> 5) << 3;  // 0 or 8

    for (int k = 0; k < 9; ++k) {
        // ---- gather loads for this k ----
        const int m = nbr[(row0 + sr) * 9 + k];
        const float4* ap = (const float4*)(f + (size_t)m * 64 + sc);
        float4 v0 = ap[0], v1 = ap[1], v2 = ap[2], v3 = ap[3];

        // ---- convert to bf16 hi/lo while other waves' loads fly ----
        float a0[8] = {v0.x,v0.y,v0.z,v0.w, v1.x,v1.y,v1.z,v1.w};
        float a1[8] = {v2.x,v2.y,v2.z,v2.w, v3.x,v3.y,v3.z,v3.w};
        ushort8 h0, l0, h1, l1;
        #pragma unroll
        for (int j = 0; j < 8; ++j) {
            ushort h = f2bf(a0[j]);
            h0[j] = h; l0[j] = f2bf(a0[j] - bf2f(h));
            ushort g = f2bf(a1[j]);
            h1[j] = g; l1[j] = f2bf(a1[j] - bf2f(g));
        }

        __syncthreads();   // previous iteration's LDS reads complete

        *(ushort8*)&Ah[sr][sc]     = h0;
        *(ushort8*)&Al[sr][sc]     = l0;
        *(ushort8*)&Ah[sr][sc + 8] = h1;
        *(ushort8*)&Al[sr][sc + 8] = l1;

        __syncthreads();

        // ---- B fragments from L2 + A fragments from LDS, 4 K-chunks ----
        const ushort* bh = Wfh + (((k * 2 + wc2) * 4) * 64 + lane) * 8;
        const ushort* bl = Wfl + (((k * 2 + wc2) * 4) * 64 + lane) * 8;
        #pragma unroll
        for (int h = 0; h < 4; ++h) {
            const int co = (h << 4) + koff;
            short8 fah = *(const short8*)&Ah[rA][co];
            short8 fal = *(const short8*)&Al[rA][co];
            short8 fbh = *(const short8*)(bh + (h << 9));
            short8 fbl = *(const short8*)(bl + (h << 9));
            acc = __builtin_amdgcn_mfma_f32_32x32x16_bf16(fah, fbh, acc, 0, 0, 0);
            acc = __builtin_amdgcn_mfma_f32_32x32x16_bf16(fah, fbl, acc, 0, 0, 0);
            acc = __builtin_amdgcn_mfma_f32_32x32x16_bf16(fal, fbh, acc, 0, 0, 0);
        }
    }

    // ---- epilogue: BN (+ residual) + ReLU ----
    // C/D layout: col = lane&31, row = (reg&3) + 8*(reg>>2) + 4*(lane>>5)
    const int d     = (wc2 << 5) + (lane & 31);
    const float iv  = gamma[d] * rsqrtf(rvar[d] + EPS);
    const float add = beta[d] - rmean[d] * iv;
    const int rb    = row0 + wr + ((lane >> 5) << 2);
    #pragma unroll
    for (int i = 0; i < 16; ++i) {
        const int n = rb + (i & 3) + ((i >> 2) << 3);
        float val = fmaf(acc[i], iv, add);
        if (SECOND) val += resid[(size_t)n * 64 + d];
        out[(size_t)n * 64 + d] = fmaxf(val, 0.f);
    }
}

extern "C" void kernel_launch(void* const* d_in, const int* in_sizes, int n_in,
                              void* d_out, int out_size, void* d_ws, size_t ws_size,
                              hipStream_t stream) {
    const float* x   = (const float*)d_in[0];
    const int*   nbr = (const int*)  d_in[1];
    const float* W1  = (const float*)d_in[2];
    const float* g1  = (const float*)d_in[3];
    const float* b1  = (const float*)d_in[4];
    const float* rm1 = (const float*)d_in[5];
    const float* rv1 = (const float*)d_in[6];
    const float* W2  = (const float*)d_in[7];
    const float* g2  = (const float*)d_in[8];
    const float* b2  = (const float*)d_in[9];
    const float* rm2 = (const float*)d_in[10];
    const float* rv2 = (const float*)d_in[11];

    const int N    = in_sizes[0] / 64;   // 200000
    const int grid = N / 64;             // 3125 exact

    // ws layout: [mid fp32 N*64][W1f_hi][W1f_lo][W2f_hi][W2f_lo]
    char* ws = (char*)d_ws;
    float*  mid = (float*)ws;            ws += (size_t)N * 64 * 4;
    ushort* W1h = (ushort*)ws;           ws += 36864 * 2;
    ushort* W1l = (ushort*)ws;           ws += 36864 * 2;
    ushort* W2h = (ushort*)ws;           ws += 36864 * 2;
    ushort* W2l = (ushort*)ws;

    prep_w2<<<288, 256, 0, stream>>>(W1, W2, W1h, W1l, W2h, W2l);

    subm_conv_mfma<false><<<grid, 256, 0, stream>>>(
        x,   nbr, W1h, W1l, g1, b1, rm1, rv1, nullptr, mid);
    subm_conv_mfma<true ><<<grid, 256, 0, stream>>>(
        mid, nbr, W2h, W2l, g2, b2, rm2, rv2, x, (float*)d_out);
}

// Round 14
// 281.580 us; speedup vs baseline: 1.0305x; 1.0305x over previous
//
#include <hip/hip_runtime.h>

#define EPS 1e-5f

typedef unsigned short ushort;
typedef unsigned int uint;
typedef __attribute__((ext_vector_type(8)))  short  short8;
typedef __attribute__((ext_vector_type(8)))  ushort ushort8;
typedef __attribute__((ext_vector_type(16))) float  f32x16;

// bf16 round-to-nearest-even split helpers
__device__ __forceinline__ ushort f2bf(float v) {
    uint b = __float_as_uint(v);
    return (ushort)((b + 0x7fffu + ((b >> 16) & 1u)) >> 16);
}
__device__ __forceinline__ float bf2f(ushort u) {
    return __uint_as_float(((uint)u) << 16);
}

// ---- prep: both W tensors -> per-lane MFMA B-fragment layout, bf16 hi/lo ----
// Wf[k][wc2][h][lane][j] : element = W[k][c][d],
//   d = wc2*32 + (lane&31),  c = h*16 + (lane>>5)*8 + j
__global__ void prep_w2(const float* __restrict__ W1, const float* __restrict__ W2,
                        ushort* __restrict__ h1, ushort* __restrict__ l1,
                        ushort* __restrict__ h2, ushort* __restrict__ l2) {
    int e = blockIdx.x * 256 + threadIdx.x;   // 0 .. 2*36864-1
    const float* W = W1; ushort* ho = h1; ushort* lo = l1;
    if (e >= 36864) { e -= 36864; W = W2; ho = h2; lo = l2; }
    const int j = e & 7, l = (e >> 3) & 63, h = (e >> 9) & 3,
              wc2 = (e >> 11) & 1, k = e >> 12;
    const int d = wc2 * 32 + (l & 31);
    const int c = h * 16 + ((l >> 5) << 3) + j;
    const float v = W[(k << 12) + (c << 6) + d];
    const ushort hh = f2bf(v);
    ho[e] = hh;
    lo[e] = f2bf(v - bf2f(hh));
}

// out[n,d] = epilogue( sum_k sum_c f[nbr[n,k],c] * W[k,c,d] )
// 64x64 block, 4 waves (2x2 of 32x32 MFMA). A-tile via LDS (18.4 KB).
// T14 pipeline: gather(k+1) issued into regs BEFORE step k's barriers;
// vmcnt-wait lands one full iteration after issue (latency hidden).
template<bool SECOND>
__global__ __launch_bounds__(256, 6) void subm_conv_mfma(
    const float*  __restrict__ f,      // [N,64] fp32 (gathered)
    const int*    __restrict__ nbr,    // [N,9]
    const ushort* __restrict__ Wfh,    // fragment-layout bf16 hi
    const ushort* __restrict__ Wfl,    // fragment-layout bf16 lo
    const float*  __restrict__ gamma,
    const float*  __restrict__ beta,
    const float*  __restrict__ rmean,
    const float*  __restrict__ rvar,
    const float*  __restrict__ resid,  // x, only when SECOND
    float* __restrict__ out)           // [N,64] fp32
{
    __shared__ __align__(16) ushort Ah[64][72];
    __shared__ __align__(16) ushort Al[64][72];

    const int t    = threadIdx.x;
    const int lane = t & 63;
    const int w    = t >> 6;
    const int wr   = (w >> 1) << 5;     // wave row offset (0/32)
    const int wc2  = w & 1;             // wave col half (0/1)
    const int row0 = blockIdx.x << 6;

    const int sr = t >> 2;              // staging row (0..63)
    const int sc = (t & 3) << 4;        // staging c offset (0,16,32,48)

    f32x16 acc = 0.f;

    const int rA   = wr + (lane & 31);
    const int koff = (lane >> 5) << 3;  // 0 or 8

    const int* __restrict__ np = nbr + (row0 + sr) * 9;

    // ---- prologue: issue gather for k=0 ----
    float4 s0, s1, s2, s3;
    {
        const int m0 = np[0];
        const float4* ap = (const float4*)(f + (size_t)m0 * 64 + sc);
        s0 = ap[0]; s1 = ap[1]; s2 = ap[2]; s3 = ap[3];
    }

    #pragma unroll
    for (int k = 0; k < 9; ++k) {
        // capture step-k staging (SSA rename; wait attaches at first use below)
        float4 c0 = s0, c1 = s1, c2 = s2, c3 = s3;

        // ---- issue gather for k+1 NOW: in flight across both barriers ----
        if (k < 8) {
            const int mn = np[k + 1];
            const float4* ap = (const float4*)(f + (size_t)mn * 64 + sc);
            s0 = ap[0]; s1 = ap[1]; s2 = ap[2]; s3 = ap[3];
        }

        __syncthreads();   // previous iteration's LDS readers done

        // ---- convert k (first use of c* -> vmcnt wait here) + LDS write ----
        {
            float a0[8] = {c0.x,c0.y,c0.z,c0.w, c1.x,c1.y,c1.z,c1.w};
            float a1[8] = {c2.x,c2.y,c2.z,c2.w, c3.x,c3.y,c3.z,c3.w};
            ushort8 h0, l0, h1, l1;
            #pragma unroll
            for (int j = 0; j < 8; ++j) {
                ushort h = f2bf(a0[j]);
                h0[j] = h; l0[j] = f2bf(a0[j] - bf2f(h));
                ushort g = f2bf(a1[j]);
                h1[j] = g; l1[j] = f2bf(a1[j] - bf2f(g));
            }
            *(ushort8*)&Ah[sr][sc]     = h0;
            *(ushort8*)&Al[sr][sc]     = l0;
            *(ushort8*)&Ah[sr][sc + 8] = h1;
            *(ushort8*)&Al[sr][sc + 8] = l1;
        }

        __syncthreads();

        // ---- compute k: B fragments from L2, A fragments from LDS ----
        const ushort* bh = Wfh + (((k * 2 + wc2) * 4) * 64 + lane) * 8;
        const ushort* bl = Wfl + (((k * 2 + wc2) * 4) * 64 + lane) * 8;
        #pragma unroll
        for (int h = 0; h < 4; ++h) {
            const int co = (h << 4) + koff;
            short8 fah = *(const short8*)&Ah[rA][co];
            short8 fal = *(const short8*)&Al[rA][co];
            short8 fbh = *(const short8*)(bh + (h << 9));
            short8 fbl = *(const short8*)(bl + (h << 9));
            acc = __builtin_amdgcn_mfma_f32_32x32x16_bf16(fah, fbh, acc, 0, 0, 0);
            acc = __builtin_amdgcn_mfma_f32_32x32x16_bf16(fah, fbl, acc, 0, 0, 0);
            acc = __builtin_amdgcn_mfma_f32_32x32x16_bf16(fal, fbh, acc, 0, 0, 0);
        }
    }

    // ---- epilogue: BN (+ residual) + ReLU ----
    // C/D layout: col = lane&31, row = (reg&3) + 8*(reg>>2) + 4*(lane>>5)
    const int d     = (wc2 << 5) + (lane & 31);
    const float iv  = gamma[d] * rsqrtf(rvar[d] + EPS);
    const float add = beta[d] - rmean[d] * iv;
    const int rb    = row0 + wr + ((lane >> 5) << 2);
    #pragma unroll
    for (int i = 0; i < 16; ++i) {
        const int n = rb + (i & 3) + ((i >> 2) << 3);
        float val = fmaf(acc[i], iv, add);
        if (SECOND) val += resid[(size_t)n * 64 + d];
        out[(size_t)n * 64 + d] = fmaxf(val, 0.f);
    }
}

extern "C" void kernel_launch(void* const* d_in, const int* in_sizes, int n_in,
                              void* d_out, int out_size, void* d_ws, size_t ws_size,
                              hipStream_t stream) {
    const float* x   = (const float*)d_in[0];
    const int*   nbr = (const int*)  d_in[1];
    const float* W1  = (const float*)d_in[2];
    const float* g1  = (const float*)d_in[3];
    const float* b1  = (const float*)d_in[4];
    const float* rm1 = (const float*)d_in[5];
    const float* rv1 = (const float*)d_in[6];
    const float* W2  = (const float*)d_in[7];
    const float* g2  = (const float*)d_in[8];
    const float* b2  = (const float*)d_in[9];
    const float* rm2 = (const float*)d_in[10];
    const float* rv2 = (const float*)d_in[11];

    const int N    = in_sizes[0] / 64;   // 200000
    const int grid = N / 64;             // 3125 exact

    // ws layout: [mid fp32 N*64][W1f_hi][W1f_lo][W2f_hi][W2f_lo]
    char* ws = (char*)d_ws;
    float*  mid = (float*)ws;            ws += (size_t)N * 64 * 4;
    ushort* W1h = (ushort*)ws;           ws += 36864 * 2;
    ushort* W1l = (ushort*)ws;           ws += 36864 * 2;
    ushort* W2h = (ushort*)ws;           ws += 36864 * 2;
    ushort* W2l = (ushort*)ws;

    prep_w2<<<288, 256, 0, stream>>>(W1, W2, W1h, W1l, W2h, W2l);

    subm_conv_mfma<false><<<grid, 256, 0, stream>>>(
        x,   nbr, W1h, W1l, g1, b1, rm1, rv1, nullptr, mid);
    subm_conv_mfma<true ><<<grid, 256, 0, stream>>>(
        mid, nbr, W2h, W2l, g2, b2, rm2, rv2, x, (float*)d_out);
}